// Round 2
// baseline (277.325 us; speedup 1.0000x reference)
//
#include <hip/hip_runtime.h>

// Focal loss (gamma=2, w0=w1=1) mean over N=2^25: -mean(log(s)*(1-s)^2),
// s = t ? p : 1-p. Two-stage reduction (no atomics).
//
// R4 post-mortem: register double-buffer compiled to VGPR=36 -- payload for
// a real 2x4-pair dbuf is >=64 VGPRs, so RA provably serialized the pipeline
// (convoy restored); perf identical to R2 (104us, 2.58 TB/s delivered,
// VALUBusy 16%, HBM 16%). FETCH_SIZE=134MB = half of 268MB input -> ~50%
// L3-resident across iterations (working set == 256MiB L3). Nothing
// saturated => compiler-enforced MLP ceiling, not a HW roofline.
// R5: force MLP. Load ALL 16 vec4-pairs (32 global_load_dwordx4, 128 VGPR
// payload) in a pure load phase, then __builtin_amdgcn_sched_barrier(0)
// (hard compile-time fence), then compute phase. RA must keep 32 results
// live -> 32 loads in flight per wave. Loads issued in consumption order so
// the compiler drains with progressive partial vmcnt waits.
// Predict: VGPR ~150-180, occupancy ~35%, dur 104 -> 55-65us,
// delivered ~4.5 TB/s, FETCH_SIZE unchanged. If unchanged instead:
// structural dual-stream ceiling -> global_load_lds staging next.

typedef float v4f __attribute__((ext_vector_type(4)));
typedef int   v4i __attribute__((ext_vector_type(4)));

constexpr int   N_TOTAL = 33554432;
constexpr int   N_VEC   = N_TOTAL / 4;        // 8388608 float4
constexpr int   THREADS = 256;
constexpr int   BLOCKS  = 2048;
constexpr int   VPB     = N_VEC / BLOCKS;     // 4096 vec4 per block
constexpr int   PAIRS   = VPB / THREADS;      // 16 vec4-pairs per thread
constexpr float NEG_INV_N = -1.0f / 33554432.0f;

__device__ __forceinline__ float term4(v4f p, v4i t) {
    float r = 0.0f;
#pragma unroll
    for (int j = 0; j < 4; ++j) {
        float s = (t[j] == 1) ? p[j] : (1.0f - p[j]);
        float q = 1.0f - s;
        r += __logf(s) * q * q;
    }
    return r;
}

__global__ __launch_bounds__(THREADS) void focal_partial_kernel(
    const v4f* __restrict__ inp,
    const v4i* __restrict__ tgt,
    float* __restrict__ partials)
{
    const int base = blockIdx.x * VPB + threadIdx.x;

    v4f pv[PAIRS];
    v4i tv[PAIRS];

    // ---- load phase: issue all 32 loads back-to-back, in consumption
    // order (p[k], t[k]) so partial vmcnt waits drain progressively ----
#pragma unroll
    for (int k = 0; k < PAIRS; ++k) {
        const int idx = base + k * THREADS;
        pv[k] = inp[idx];
        tv[k] = tgt[idx];
    }

    // hard scheduling fence: no compute may be hoisted above, no load may
    // sink below -> RA must keep all 32 load results live (forces MLP=32).
    __builtin_amdgcn_sched_barrier(0);

    // ---- compute phase ----
    float acc = 0.0f;
#pragma unroll
    for (int k = 0; k < PAIRS; ++k)
        acc += term4(pv[k], tv[k]);

    // wave-64 shuffle reduction
#pragma unroll
    for (int off = 32; off > 0; off >>= 1)
        acc += __shfl_down(acc, off, 64);

    __shared__ float ws[THREADS / 64];
    int lane = threadIdx.x & 63;
    int wave = threadIdx.x >> 6;
    if (lane == 0) ws[wave] = acc;
    __syncthreads();

    if (threadIdx.x == 0)
        partials[blockIdx.x] = ws[0] + ws[1] + ws[2] + ws[3];
}

__global__ __launch_bounds__(THREADS) void focal_final_kernel(
    const float* __restrict__ partials,
    float* __restrict__ out)
{
    float acc = 0.0f;
#pragma unroll
    for (int k = 0; k < BLOCKS / THREADS; ++k)
        acc += partials[k * THREADS + threadIdx.x];

#pragma unroll
    for (int off = 32; off > 0; off >>= 1)
        acc += __shfl_down(acc, off, 64);

    __shared__ float ws[THREADS / 64];
    int lane = threadIdx.x & 63;
    int wave = threadIdx.x >> 6;
    if (lane == 0) ws[wave] = acc;
    __syncthreads();

    if (threadIdx.x == 0)
        out[0] = (ws[0] + ws[1] + ws[2] + ws[3]) * NEG_INV_N;
}

extern "C" void kernel_launch(void* const* d_in, const int* in_sizes, int n_in,
                              void* d_out, int out_size, void* d_ws, size_t ws_size,
                              hipStream_t stream) {
    const v4f* inp = (const v4f*)d_in[0];
    const v4i* tgt = (const v4i*)d_in[1];
    float*     out = (float*)d_out;
    float*     partials = (float*)d_ws;   // 8 KB scratch

    focal_partial_kernel<<<BLOCKS, THREADS, 0, stream>>>(inp, tgt, partials);
    focal_final_kernel<<<1, THREADS, 0, stream>>>(partials, out);
}

// Round 3
// 273.710 us; speedup vs baseline: 1.0132x; 1.0132x over previous
//
#include <hip/hip_runtime.h>

// Focal loss (gamma=2, w0=w1=1) mean over N=2^25: -mean(log(s)*(1-s)^2),
// s = t ? p : 1-p. Two-stage reduction (no atomics).
//
// R5 post-mortem: MLP theory is DEAD by arithmetic. 8192 resident waves x
// ~2 loads = ~16MB aggregate in flight; queues are backpressured (effective
// latency = inflight/BW ~ 6us), so per-wave MLP cannot matter -- which is
// exactly why VGPR 24/36/68 & occupancy 51/23% all gave the same 104us /
// 2.58 TB/s. Delivered BW is capped by a downstream resource.
// Known-good streamers on this chip (RMSNorm 4.89 TB/s, copy 6.29 TB/s)
// differ in ONE structural way: they advance 1-2 coherent fronts
// (grid-phase striding), while our block-contiguous partitioning advances
// 4096 independent 1KB-granular fronts (2 streams x 2048 blocks) scattered
// over 256MB -> DRAM row/page thrash + L3 bank spread.
// R6: grid-stride indexing, idx = gtid + k*GRID_THREADS (16 steps). Whole
// grid sweeps one contiguous 8MB window per stream per step -> 2 fronts.
// Everything else identical to R2 (plain loads, simple unrolled loop).
// Predict: dur 104 -> 55-75us, delivered -> 3.6-4.9 TB/s, VALUBusy ~25%,
// FETCH <= 134MB. If NULL: pattern-insensitive cap -> test nt next; then
// declare structural two-stream ceiling.

typedef float v4f __attribute__((ext_vector_type(4)));
typedef int   v4i __attribute__((ext_vector_type(4)));

constexpr int   N_TOTAL   = 33554432;
constexpr int   N_VEC     = N_TOTAL / 4;          // 8388608 float4
constexpr int   THREADS   = 256;
constexpr int   BLOCKS    = 2048;
constexpr int   GTHREADS  = BLOCKS * THREADS;     // 524288
constexpr int   STEPS     = N_VEC / GTHREADS;     // 16
constexpr float NEG_INV_N = -1.0f / 33554432.0f;

__device__ __forceinline__ float term4(v4f p, v4i t) {
    float r = 0.0f;
#pragma unroll
    for (int j = 0; j < 4; ++j) {
        float s = (t[j] == 1) ? p[j] : (1.0f - p[j]);
        float q = 1.0f - s;
        r += __logf(s) * q * q;
    }
    return r;
}

__global__ __launch_bounds__(THREADS) void focal_partial_kernel(
    const v4f* __restrict__ inp,
    const v4i* __restrict__ tgt,
    float* __restrict__ partials)
{
    const int gtid = blockIdx.x * THREADS + threadIdx.x;

    float acc = 0.0f;
#pragma unroll
    for (int k = 0; k < STEPS; ++k) {
        const int idx = gtid + k * GTHREADS;   // whole grid sweeps one 8MB
        v4f p = inp[idx];                      // window per stream per step
        v4i t = tgt[idx];
        acc += term4(p, t);
    }

    // wave-64 shuffle reduction
#pragma unroll
    for (int off = 32; off > 0; off >>= 1)
        acc += __shfl_down(acc, off, 64);

    __shared__ float ws[THREADS / 64];
    int lane = threadIdx.x & 63;
    int wave = threadIdx.x >> 6;
    if (lane == 0) ws[wave] = acc;
    __syncthreads();

    if (threadIdx.x == 0)
        partials[blockIdx.x] = ws[0] + ws[1] + ws[2] + ws[3];
}

__global__ __launch_bounds__(THREADS) void focal_final_kernel(
    const float* __restrict__ partials,
    float* __restrict__ out)
{
    float acc = 0.0f;
#pragma unroll
    for (int k = 0; k < BLOCKS / THREADS; ++k)
        acc += partials[k * THREADS + threadIdx.x];

#pragma unroll
    for (int off = 32; off > 0; off >>= 1)
        acc += __shfl_down(acc, off, 64);

    __shared__ float ws[THREADS / 64];
    int lane = threadIdx.x & 63;
    int wave = threadIdx.x >> 6;
    if (lane == 0) ws[wave] = acc;
    __syncthreads();

    if (threadIdx.x == 0)
        out[0] = (ws[0] + ws[1] + ws[2] + ws[3]) * NEG_INV_N;
}

extern "C" void kernel_launch(void* const* d_in, const int* in_sizes, int n_in,
                              void* d_out, int out_size, void* d_ws, size_t ws_size,
                              hipStream_t stream) {
    const v4f* inp = (const v4f*)d_in[0];
    const v4i* tgt = (const v4i*)d_in[1];
    float*     out = (float*)d_out;
    float*     partials = (float*)d_ws;   // 8 KB scratch

    focal_partial_kernel<<<BLOCKS, THREADS, 0, stream>>>(inp, tgt, partials);
    focal_final_kernel<<<1, THREADS, 0, stream>>>(partials, out);
}